// Round 3
// baseline (911.716 us; speedup 1.0000x reference)
//
#include <hip/hip_runtime.h>

// GCN 3-layer forward on MI355X.
// out[c] = dinv[c] * (sum_{(r,c) in E} hn[r] + hn[c]) + b,  hn = dinv[r]*(X@W)[r]
//  - Float tensors are f32 (proven by round-2 NaN: f32-read-as-bf16 makes NaNs, and a
//    corruption-free kernel still NaN'd). Inputs converted once to bf16 for MFMA;
//    intermediates bf16 (half the gather bytes); all accumulation f32; output written f32.
//  - edge_index int32 or int64: 1-thread runtime detection, all indices clamped.
//  - CSR build per call (count -> single-block scan -> fill), then gather aggregation.
//  - MFMA bf16 16x16x32 GEMM, wave computes 16Mx64N, dinv-scale epilogue.

#define IN_F 50
#define HID  256
#define OUT_F 121
#define KP1  64    // layer-1 K padded 50->64
#define NP3  128   // layer-3 N padded 121->128

typedef __attribute__((ext_vector_type(8))) short bf16x8;
typedef __attribute__((ext_vector_type(4))) float f32x4;

__device__ __forceinline__ float bf2f(unsigned short u) {
    union { unsigned int i; float f; } x; x.i = ((unsigned int)u) << 16; return x.f;
}
__device__ __forceinline__ unsigned short f2bf(float f) {
    union { float f; unsigned int i; } x; x.f = f;
    unsigned int r = x.i + 0x7FFFu + ((x.i >> 16) & 1u);  // RNE
    return (unsigned short)(r >> 16);
}

// ---- edge dtype detection --------------------------------------------------
// int64 LE values in [0,N): int32 view = v0,0,v1,0,...  64 consecutive zero
// odd-words from genuine int32 index data is ~impossible.
__global__ void k_detect(const int* __restrict__ ei, int* __restrict__ flag, int N) {
    if (blockIdx.x == 0 && threadIdx.x == 0) {
        int is64 = 1;
        for (int i = 0; i < 64; i++) {
            int lo = ei[2 * i], hi = ei[2 * i + 1];
            if (hi != 0 || (unsigned)lo >= (unsigned)N) { is64 = 0; break; }
        }
        *flag = is64;
    }
}

// ---- CSR build -------------------------------------------------------------

__global__ void k_count(const int* __restrict__ ei, const int* __restrict__ flag,
                        int* __restrict__ cnt, int E, int N) {
    int t = blockIdx.x * blockDim.x + threadIdx.x;
    if (t >= E) return;
    int f = *flag;
    int c = f ? ei[2 * (E + t)] : ei[E + t];
    c = min(max(c, 0), N - 1);
    atomicAdd(&cnt[c], 1);
}

__global__ __launch_bounds__(1024) void k_scan(const int* __restrict__ cnt,
                                               int* __restrict__ offs, int n) {
    __shared__ int wsum[16];
    __shared__ int s_carry;
    int lane = threadIdx.x & 63, wid = threadIdx.x >> 6;
    if (threadIdx.x == 0) s_carry = 0;
    __syncthreads();
    for (int base = 0; base < n; base += 4096) {
        int i0 = base + (int)threadIdx.x * 4;
        int v0 = (i0 + 0 < n) ? cnt[i0 + 0] : 0;
        int v1 = (i0 + 1 < n) ? cnt[i0 + 1] : 0;
        int v2 = (i0 + 2 < n) ? cnt[i0 + 2] : 0;
        int v3 = (i0 + 3 < n) ? cnt[i0 + 3] : 0;
        int s1 = v0 + v1, s2 = s1 + v2, tsum = s2 + v3;
        int x = tsum;
        #pragma unroll
        for (int d = 1; d < 64; d <<= 1) {
            int y = __shfl_up(x, d, 64);
            if (lane >= d) x += y;
        }
        if (lane == 63) wsum[wid] = x;
        __syncthreads();
        int wpre = 0;
        #pragma unroll
        for (int j = 0; j < 16; j++) wpre += (j < wid) ? wsum[j] : 0;
        int carry = s_carry;
        int e0 = carry + wpre + x - tsum;   // exclusive prefix of this thread's 4 elems
        if (i0 + 0 < n) offs[i0 + 0] = e0;
        if (i0 + 1 < n) offs[i0 + 1] = e0 + v0;
        if (i0 + 2 < n) offs[i0 + 2] = e0 + s1;
        if (i0 + 3 < n) offs[i0 + 3] = e0 + s2;
        __syncthreads();
        if (threadIdx.x == 1023) s_carry = carry + wpre + x;
        __syncthreads();
    }
    if (threadIdx.x == 0) offs[n] = s_carry;
}

__global__ void k_fill(const int* __restrict__ ei, const int* __restrict__ flag,
                       const int* __restrict__ offs,
                       int* __restrict__ fill, int* __restrict__ rowidx, int E, int N) {
    int t = blockIdx.x * blockDim.x + threadIdx.x;
    if (t >= E) return;
    int f = *flag;
    int c = f ? ei[2 * (E + t)] : ei[E + t];
    int r = f ? ei[2 * t] : ei[t];
    c = min(max(c, 0), N - 1);
    r = min(max(r, 0), N - 1);
    int pos = offs[c] + atomicAdd(&fill[c], 1);
    if ((unsigned)pos < (unsigned)E) rowidx[pos] = r;
}

__global__ void k_dinv(const int* __restrict__ cnt, float* __restrict__ dinv, int N) {
    int t = blockIdx.x * blockDim.x + threadIdx.x;
    if (t < N) dinv[t] = rsqrtf((float)(cnt[t] + 1));   // +1 = self-loop
}

// ---- input prep (f32 -> bf16) ----------------------------------------------

__global__ void k_padx(const float* __restrict__ x, unsigned short* __restrict__ Xp, int N) {
    int idx = blockIdx.x * blockDim.x + threadIdx.x;
    if (idx >= N * KP1) return;
    int node = idx >> 6, k = idx & 63;
    Xp[idx] = (k < IN_F) ? f2bf(x[node * IN_F + k]) : (unsigned short)0;
}

// W [K x Nw] row-major f32 -> Bt [Np x Kp] row-major bf16 (transposed, zero-padded)
__global__ void k_tr(const float* __restrict__ W, unsigned short* __restrict__ Bt,
                     int K, int Nw, int Kp, int Np) {
    int idx = blockIdx.x * blockDim.x + threadIdx.x;
    if (idx >= Np * Kp) return;
    int nn = idx / Kp, k = idx - nn * Kp;
    Bt[idx] = (k < K && nn < Nw) ? f2bf(W[k * Nw + nn]) : (unsigned short)0;
}

// ---- GEMM: C[m][n] = dinv[m] * sum_k A[m][k]*Bt[n][k]  (bf16 in, bf16 out) -
// wave: 16 rows x 64 cols; block = 4 waves (64 rows); grid.y covers N in 64s.

__global__ __launch_bounds__(256) void k_gemm(const unsigned short* __restrict__ A,
                                              const unsigned short* __restrict__ Bt,
                                              const float* __restrict__ dinv,
                                              unsigned short* __restrict__ C,
                                              int M, int K, int Nout) {
    int wid = threadIdx.x >> 6, lane = threadIdx.x & 63;
    int mt = blockIdx.x * 4 + wid;
    if (mt * 16 >= M) return;
    int m0 = mt * 16;
    int n0 = blockIdx.y * 64;
    int quad = lane >> 4, ml = lane & 15;
    const unsigned short* pa = A + (size_t)(m0 + ml) * K + quad * 8;
    const unsigned short* pb = Bt + (size_t)(n0 + ml) * K + quad * 8;
    size_t bstep = (size_t)16 * K;
    f32x4 acc0 = {0.f, 0.f, 0.f, 0.f};
    f32x4 acc1 = acc0, acc2 = acc0, acc3 = acc0;
    for (int k = 0; k < K; k += 32) {
        bf16x8 av = *(const bf16x8*)(pa + k);
        bf16x8 b0 = *(const bf16x8*)(pb + k);
        bf16x8 b1 = *(const bf16x8*)(pb + bstep + k);
        bf16x8 b2 = *(const bf16x8*)(pb + 2 * bstep + k);
        bf16x8 b3 = *(const bf16x8*)(pb + 3 * bstep + k);
        acc0 = __builtin_amdgcn_mfma_f32_16x16x32_bf16(av, b0, acc0, 0, 0, 0);
        acc1 = __builtin_amdgcn_mfma_f32_16x16x32_bf16(av, b1, acc1, 0, 0, 0);
        acc2 = __builtin_amdgcn_mfma_f32_16x16x32_bf16(av, b2, acc2, 0, 0, 0);
        acc3 = __builtin_amdgcn_mfma_f32_16x16x32_bf16(av, b3, acc3, 0, 0, 0);
    }
    int r0 = m0 + quad * 4;
    float dd[4] = {dinv[r0], dinv[r0 + 1], dinv[r0 + 2], dinv[r0 + 3]};
    unsigned short* pc = C + (size_t)r0 * Nout + n0 + ml;
    f32x4 accs[4] = {acc0, acc1, acc2, acc3};
    #pragma unroll
    for (int t = 0; t < 4; t++) {
        #pragma unroll
        for (int i = 0; i < 4; i++) {
            pc[(size_t)i * Nout + t * 16] = f2bf(accs[t][i] * dd[i]);  // row r0+i, col n0+16t+ml
        }
    }
}

// ---- aggregation: out = relu?(dinv[c]*(self + sum_nbr) + b) ----------------
// one wave per node; lane owns 4 contiguous cols (HID=256). bf16 out (next layer in).

__global__ void k_agg_hid(const unsigned short* __restrict__ Hn,
                          const int* __restrict__ offs, const int* __restrict__ rowidx,
                          const float* __restrict__ dinv, const float* __restrict__ bias,
                          unsigned short* __restrict__ Hout, int N, int relu) {
    int wid = threadIdx.x >> 6, lane = threadIdx.x & 63;
    int node = blockIdx.x * 4 + wid;
    if (node >= N) return;
    int c = lane * 4;
    ushort4 s = *(const ushort4*)(Hn + (size_t)node * HID + c);
    float a0 = bf2f(s.x), a1 = bf2f(s.y), a2 = bf2f(s.z), a3 = bf2f(s.w);
    int e = offs[node], end = offs[node + 1];
    if (end < e) end = e;
    for (; e + 2 <= end; e += 2) {
        int r0 = rowidx[e], r1 = rowidx[e + 1];
        ushort4 u = *(const ushort4*)(Hn + (size_t)r0 * HID + c);
        ushort4 v = *(const ushort4*)(Hn + (size_t)r1 * HID + c);
        a0 += bf2f(u.x) + bf2f(v.x);
        a1 += bf2f(u.y) + bf2f(v.y);
        a2 += bf2f(u.z) + bf2f(v.z);
        a3 += bf2f(u.w) + bf2f(v.w);
    }
    if (e < end) {
        int r0 = rowidx[e];
        ushort4 u = *(const ushort4*)(Hn + (size_t)r0 * HID + c);
        a0 += bf2f(u.x); a1 += bf2f(u.y); a2 += bf2f(u.z); a3 += bf2f(u.w);
    }
    float dv = dinv[node];
    float4 bb = *(const float4*)(bias + c);
    float o0 = fmaf(a0, dv, bb.x);
    float o1 = fmaf(a1, dv, bb.y);
    float o2 = fmaf(a2, dv, bb.z);
    float o3 = fmaf(a3, dv, bb.w);
    if (relu) {
        o0 = fmaxf(o0, 0.f); o1 = fmaxf(o1, 0.f);
        o2 = fmaxf(o2, 0.f); o3 = fmaxf(o3, 0.f);
    }
    ushort4 o = make_ushort4(f2bf(o0), f2bf(o1), f2bf(o2), f2bf(o3));
    *(ushort4*)(Hout + (size_t)node * HID + c) = o;
}

// final layer: Hn is [N x 128] bf16 (padded), write [N x 121] f32, no relu.
__global__ void k_agg_out(const unsigned short* __restrict__ Hn,
                          const int* __restrict__ offs, const int* __restrict__ rowidx,
                          const float* __restrict__ dinv, const float* __restrict__ bias,
                          float* __restrict__ out, int N) {
    int wid = threadIdx.x >> 6, lane = threadIdx.x & 63;
    int node = blockIdx.x * 4 + wid;
    if (node >= N) return;
    int c = lane * 2;
    ushort2 s = *(const ushort2*)(Hn + (size_t)node * NP3 + c);
    float a0 = bf2f(s.x), a1 = bf2f(s.y);
    int e = offs[node], end = offs[node + 1];
    if (end < e) end = e;
    for (; e + 2 <= end; e += 2) {
        int r0 = rowidx[e], r1 = rowidx[e + 1];
        ushort2 u = *(const ushort2*)(Hn + (size_t)r0 * NP3 + c);
        ushort2 v = *(const ushort2*)(Hn + (size_t)r1 * NP3 + c);
        a0 += bf2f(u.x) + bf2f(v.x);
        a1 += bf2f(u.y) + bf2f(v.y);
    }
    if (e < end) {
        int r0 = rowidx[e];
        ushort2 u = *(const ushort2*)(Hn + (size_t)r0 * NP3 + c);
        a0 += bf2f(u.x); a1 += bf2f(u.y);
    }
    float dv = dinv[node];
    if (c < OUT_F)
        out[(size_t)node * OUT_F + c] = fmaf(a0, dv, bias[c]);
    if (c + 1 < OUT_F)
        out[(size_t)node * OUT_F + c + 1] = fmaf(a1, dv, bias[c + 1]);
}

// ---- launch ----------------------------------------------------------------

extern "C" void kernel_launch(void* const* d_in, const int* in_sizes, int n_in,
                              void* d_out, int out_size, void* d_ws, size_t ws_size,
                              hipStream_t stream) {
    const float* x  = (const float*)d_in[0];
    const int*   ei = (const int*)d_in[1];
    const float* W1 = (const float*)d_in[2];
    const float* b1 = (const float*)d_in[3];
    const float* W2 = (const float*)d_in[4];
    const float* b2 = (const float*)d_in[5];
    const float* W3 = (const float*)d_in[6];
    const float* b3 = (const float*)d_in[7];
    float* out = (float*)d_out;

    const int N = in_sizes[0] / IN_F;     // 100000
    const int E = in_sizes[1] / 2;        // 1600000 (flat element count / 2)

    char* w = (char*)d_ws;
    size_t off = 0;
    auto alloc = [&](size_t bytes) -> char* {
        char* p = w + off;
        off += (bytes + 255) & ~(size_t)255;
        return p;
    };
    int*   cnt    = (int*)  alloc((size_t)N * 4);
    int*   fillc  = (int*)  alloc((size_t)N * 4);
    int*   offs   = (int*)  alloc((size_t)(N + 1) * 4);
    float* dinv   = (float*)alloc((size_t)N * 4);
    int*   flag   = (int*)  alloc(256);
    int*   rowidx = (int*)  alloc((size_t)E * 4);
    unsigned short* Bt1  = (unsigned short*)alloc((size_t)HID * KP1 * 2);
    unsigned short* Bt2  = (unsigned short*)alloc((size_t)HID * HID * 2);
    unsigned short* Bt3  = (unsigned short*)alloc((size_t)NP3 * HID * 2);
    unsigned short* bufA = (unsigned short*)alloc((size_t)N * HID * 2);
    unsigned short* bufB = (unsigned short*)alloc((size_t)N * HID * 2);
    unsigned short* Xp   = bufB;  // alias: Xp dead before bufB first written (agg1)

    hipMemsetAsync(cnt, 0, (size_t)N * 4, stream);
    hipMemsetAsync(fillc, 0, (size_t)N * 4, stream);

    k_detect<<<1, 64, 0, stream>>>(ei, flag, N);
    k_count<<<(E + 255) / 256, 256, 0, stream>>>(ei, flag, cnt, E, N);
    k_scan<<<1, 1024, 0, stream>>>(cnt, offs, N);
    k_dinv<<<(N + 255) / 256, 256, 0, stream>>>(cnt, dinv, N);
    k_fill<<<(E + 255) / 256, 256, 0, stream>>>(ei, flag, offs, fillc, rowidx, E, N);

    k_padx<<<(N * KP1 + 255) / 256, 256, 0, stream>>>(x, Xp, N);
    k_tr<<<(HID * KP1 + 255) / 256, 256, 0, stream>>>(W1, Bt1, IN_F, HID, KP1, HID);
    k_tr<<<(HID * HID + 255) / 256, 256, 0, stream>>>(W2, Bt2, HID, HID, HID, HID);
    k_tr<<<(NP3 * HID + 255) / 256, 256, 0, stream>>>(W3, Bt3, HID, OUT_F, HID, NP3);

    int mtiles = (N + 15) / 16;                 // 6250
    dim3 g12((unsigned)((mtiles + 3) / 4), HID / 64);   // (1563, 4)
    dim3 g3((unsigned)((mtiles + 3) / 4), NP3 / 64);    // (1563, 2)
    int aggg = (N + 3) / 4;                     // 25000

    // layer 1
    k_gemm<<<g12, 256, 0, stream>>>(Xp, Bt1, dinv, bufA, N, KP1, HID);
    k_agg_hid<<<aggg, 256, 0, stream>>>(bufA, offs, rowidx, dinv, b1, bufB, N, 1);
    // layer 2
    k_gemm<<<g12, 256, 0, stream>>>(bufB, Bt2, dinv, bufA, N, HID, HID);
    k_agg_hid<<<aggg, 256, 0, stream>>>(bufA, offs, rowidx, dinv, b2, bufB, N, 1);
    // layer 3
    k_gemm<<<g3, 256, 0, stream>>>(bufB, Bt3, dinv, bufA, N, HID, NP3);
    k_agg_out<<<aggg, 256, 0, stream>>>(bufA, offs, rowidx, dinv, b3, out, N);

    (void)n_in; (void)out_size; (void)ws_size;
}

// Round 7
// 818.048 us; speedup vs baseline: 1.1145x; 1.1145x over previous
//
#include <hip/hip_runtime.h>

// GCN 3-layer forward on MI355X.
// Algebra: A_hat (X W) = (A_hat X) W. Pipeline:
//   aggx:  Y1 = A_hat X              (64-wide gather rows, ws 12.8 MB)
//   GEMM1: H1s = dinv * relu(Y1 W1 + b1)
//   agg256: Y2 = dinv[c]*(sum H1s[r] + H1s[c])
//   GEMM2: H2 = relu(Y2 W2 + b2)
//   GEMM3: G3 = dinv * (H2 W3)
//   aggout: out = dinv[c]*(sum G3[r] + G3[c]) + b3   (f32)
// CSR build uses the round-3-proven structure: atomics ONLY on memset-initialized
// arrays (cnt, fillc); plain-store arrays (offs, dinv) only read non-atomically.
// rowidx is memset and additionally clamped at read time (cross-XCD staleness
// degrades to finite-wrong, never OOB — round-6 post-timing divergence fix).
// MFMA 16x16x32 bf16; wave = 16 rows x NACC*16 cols, A read once. f32 in/out,
// bf16 internals, f32 accumulation everywhere.

#define IN_F 50
#define HID  256
#define OUT_F 121
#define KP1  64    // layer-1 width padded 50->64
#define NP3  128   // layer-3 N padded 121->128

typedef __attribute__((ext_vector_type(8))) short bf16x8;
typedef __attribute__((ext_vector_type(4))) float f32x4;

__device__ __forceinline__ float bf2f(unsigned short u) {
    union { unsigned int i; float f; } x; x.i = ((unsigned int)u) << 16; return x.f;
}
__device__ __forceinline__ unsigned short f2bf(float f) {
    union { float f; unsigned int i; } x; x.f = f;
    unsigned int r = x.i + 0x7FFFu + ((x.i >> 16) & 1u);  // RNE
    return (unsigned short)(r >> 16);
}

// ---- edge dtype detection (int64 vs int32), 64-lane parallel ----------------
__global__ void k_detect(const int* __restrict__ ei, int* __restrict__ flag, int N) {
    int i = threadIdx.x;
    int lo = ei[2 * i], hi = ei[2 * i + 1];
    int bad = (hi != 0) || ((unsigned)lo >= (unsigned)N);
    unsigned long long m = __ballot(bad);
    if (threadIdx.x == 0) *flag = (m == 0ULL) ? 1 : 0;
}

// ---- CSR build --------------------------------------------------------------

__global__ void k_count(const int* __restrict__ ei, const int* __restrict__ flag,
                        int* __restrict__ cnt, int E, int N) {
    int t = blockIdx.x * blockDim.x + threadIdx.x;
    if (t >= E) return;
    int f = *flag;
    int c = f ? ei[2 * (E + t)] : ei[E + t];
    c = min(max(c, 0), N - 1);
    atomicAdd(&cnt[c], 1);
}

// exclusive scan of cnt -> offs; also dinv = rsqrt(cnt+1)
__global__ __launch_bounds__(1024) void k_scan(const int* __restrict__ cnt,
                                               int* __restrict__ offs,
                                               float* __restrict__ dinv, int n) {
    __shared__ int wsum[16];
    __shared__ int s_carry;
    int lane = threadIdx.x & 63, wid = threadIdx.x >> 6;
    if (threadIdx.x == 0) s_carry = 0;
    __syncthreads();
    for (int base = 0; base < n; base += 4096) {
        int i0 = base + (int)threadIdx.x * 4;
        int v0 = (i0 + 0 < n) ? cnt[i0 + 0] : 0;
        int v1 = (i0 + 1 < n) ? cnt[i0 + 1] : 0;
        int v2 = (i0 + 2 < n) ? cnt[i0 + 2] : 0;
        int v3 = (i0 + 3 < n) ? cnt[i0 + 3] : 0;
        int s1 = v0 + v1, s2 = s1 + v2, tsum = s2 + v3;
        int x = tsum;
        #pragma unroll
        for (int d = 1; d < 64; d <<= 1) {
            int y = __shfl_up(x, d, 64);
            if (lane >= d) x += y;
        }
        if (lane == 63) wsum[wid] = x;
        __syncthreads();
        int wpre = 0;
        #pragma unroll
        for (int j = 0; j < 16; j++) wpre += (j < wid) ? wsum[j] : 0;
        int carry = s_carry;
        int e0 = carry + wpre + x - tsum;
        if (i0 + 0 < n) { offs[i0+0]=e0;    dinv[i0+0]=rsqrtf((float)(v0+1)); }
        if (i0 + 1 < n) { offs[i0+1]=e0+v0; dinv[i0+1]=rsqrtf((float)(v1+1)); }
        if (i0 + 2 < n) { offs[i0+2]=e0+s1; dinv[i0+2]=rsqrtf((float)(v2+1)); }
        if (i0 + 3 < n) { offs[i0+3]=e0+s2; dinv[i0+3]=rsqrtf((float)(v3+1)); }
        __syncthreads();
        if (threadIdx.x == 1023) s_carry = carry + wpre + x;
        __syncthreads();
    }
    if (threadIdx.x == 0) offs[n] = s_carry;
}

// fill via memset-zeroed fillc (atomics only on memset-initialized memory)
__global__ void k_fill(const int* __restrict__ ei, const int* __restrict__ flag,
                       const int* __restrict__ offs,
                       int* __restrict__ fillc, int* __restrict__ rowidx, int E, int N) {
    int t = blockIdx.x * blockDim.x + threadIdx.x;
    if (t >= E) return;
    int f = *flag;
    int c = f ? ei[2 * (E + t)] : ei[E + t];
    int r = f ? ei[2 * t] : ei[t];
    c = min(max(c, 0), N - 1);
    r = min(max(r, 0), N - 1);
    int pos = offs[c] + atomicAdd(&fillc[c], 1);
    if ((unsigned)pos < (unsigned)E) rowidx[pos] = r;
}

// ---- input prep -------------------------------------------------------------

__global__ void k_padx(const float* __restrict__ x, const float* __restrict__ dinv,
                       unsigned short* __restrict__ Xs, int N) {
    int idx = blockIdx.x * blockDim.x + threadIdx.x;
    if (idx >= N * KP1) return;
    int node = idx >> 6, k = idx & 63;
    Xs[idx] = (k < IN_F) ? f2bf(dinv[node] * x[node * IN_F + k]) : (unsigned short)0;
}

__global__ void k_tr(const float* __restrict__ W, unsigned short* __restrict__ Bt,
                     int K, int Nw, int Kp, int Np) {
    int idx = blockIdx.x * blockDim.x + threadIdx.x;
    if (idx >= Np * Kp) return;
    int nn = idx / Kp, k = idx - nn * Kp;
    Bt[idx] = (k < K && nn < Nw) ? f2bf(W[k * Nw + nn]) : (unsigned short)0;
}

// ---- GEMM body (inlined into 3 concrete kernels) ----------------------------
__device__ __forceinline__ void gemm_body(const unsigned short* __restrict__ A,
                                          const unsigned short* __restrict__ Bt,
                                          const float* __restrict__ dinv,
                                          const float* __restrict__ bias,
                                          unsigned short* __restrict__ C,
                                          int M, int K,
                                          const int NACC, const int BIAS,
                                          const int RELU, const int SCALE) {
    const int Nout = NACC * 16;
    int wid = threadIdx.x >> 6, lane = threadIdx.x & 63;
    int mt = blockIdx.x * 4 + wid;
    if (mt * 16 >= M) return;
    int m0 = mt * 16;
    int quad = lane >> 4, ml = lane & 15;
    const unsigned short* pa = A + (size_t)(m0 + ml) * K + quad * 8;
    const unsigned short* pb = Bt + (size_t)ml * K + quad * 8;
    size_t bstep = (size_t)16 * K;
    f32x4 acc[16];
    #pragma unroll
    for (int t = 0; t < 16; t++) acc[t] = (f32x4){0.f, 0.f, 0.f, 0.f};
    for (int k = 0; k < K; k += 32) {
        bf16x8 av = *(const bf16x8*)(pa + k);
        #pragma unroll
        for (int t = 0; t < 16; t++) {
            if (t < NACC) {
                bf16x8 bv = *(const bf16x8*)(pb + (size_t)t * bstep + k);
                acc[t] = __builtin_amdgcn_mfma_f32_16x16x32_bf16(av, bv, acc[t], 0, 0, 0);
            }
        }
    }
    int r0 = m0 + quad * 4;
    float dd[4] = {1.f, 1.f, 1.f, 1.f};
    if (SCALE) { dd[0]=dinv[r0]; dd[1]=dinv[r0+1]; dd[2]=dinv[r0+2]; dd[3]=dinv[r0+3]; }
    unsigned short* pc = C + (size_t)r0 * Nout + ml;
    #pragma unroll
    for (int t = 0; t < 16; t++) {
        if (t < NACC) {
            float bb = BIAS ? bias[t * 16 + ml] : 0.f;
            #pragma unroll
            for (int i = 0; i < 4; i++) {
                float v = acc[t][i];
                if (BIAS) v += bb;
                if (RELU) v = fmaxf(v, 0.f);
                v *= dd[i];
                pc[(size_t)i * Nout + t * 16] = f2bf(v);   // row r0+i, col t*16+ml
            }
        }
    }
}

__global__ __launch_bounds__(256) void k_gemm1(const unsigned short* __restrict__ A,
                                               const unsigned short* __restrict__ Bt,
                                               const float* __restrict__ dinv,
                                               const float* __restrict__ bias,
                                               unsigned short* __restrict__ C, int M, int K) {
    gemm_body(A, Bt, dinv, bias, C, M, K, 16, 1, 1, 1);
}
__global__ __launch_bounds__(256) void k_gemm2(const unsigned short* __restrict__ A,
                                               const unsigned short* __restrict__ Bt,
                                               const float* __restrict__ dinv,
                                               const float* __restrict__ bias,
                                               unsigned short* __restrict__ C, int M, int K) {
    gemm_body(A, Bt, dinv, bias, C, M, K, 16, 1, 1, 0);
}
__global__ __launch_bounds__(256) void k_gemm3(const unsigned short* __restrict__ A,
                                               const unsigned short* __restrict__ Bt,
                                               const float* __restrict__ dinv,
                                               const float* __restrict__ bias,
                                               unsigned short* __restrict__ C, int M, int K) {
    gemm_body(A, Bt, dinv, bias, C, M, K, 8, 0, 0, 1);
}

// ---- aggregation kernels (gather, unroll-4, read-side index clamp) ----------

__device__ __forceinline__ int rclamp(int r, int N) { return min(max(r, 0), N - 1); }

__global__ void k_aggx(const unsigned short* __restrict__ Xs,
                       const int* __restrict__ offs, const int* __restrict__ rowidx,
                       const float* __restrict__ dinv, unsigned short* __restrict__ Y, int N) {
    int wid = threadIdx.x >> 6, lane = threadIdx.x & 63;
    int node = blockIdx.x * 4 + wid;
    if (node >= N) return;
    float a = bf2f(Xs[(size_t)node * KP1 + lane]);
    int e = offs[node], end = offs[node + 1];
    for (; e + 4 <= end; e += 4) {
        int r0 = rclamp(rowidx[e], N),   r1 = rclamp(rowidx[e+1], N);
        int r2 = rclamp(rowidx[e+2], N), r3 = rclamp(rowidx[e+3], N);
        float g0 = bf2f(Xs[(size_t)r0 * KP1 + lane]);
        float g1 = bf2f(Xs[(size_t)r1 * KP1 + lane]);
        float g2 = bf2f(Xs[(size_t)r2 * KP1 + lane]);
        float g3 = bf2f(Xs[(size_t)r3 * KP1 + lane]);
        a += (g0 + g1) + (g2 + g3);
    }
    for (; e < end; e++) a += bf2f(Xs[(size_t)rclamp(rowidx[e], N) * KP1 + lane]);
    Y[(size_t)node * KP1 + lane] = f2bf(a * dinv[node]);
}

__global__ void k_agg256(const unsigned short* __restrict__ Hn,
                         const int* __restrict__ offs, const int* __restrict__ rowidx,
                         const float* __restrict__ dinv, unsigned short* __restrict__ Y, int N) {
    int wid = threadIdx.x >> 6, lane = threadIdx.x & 63;
    int node = blockIdx.x * 4 + wid;
    if (node >= N) return;
    int c = lane * 4;
    ushort4 s = *(const ushort4*)(Hn + (size_t)node * HID + c);
    float a0 = bf2f(s.x), a1 = bf2f(s.y), a2 = bf2f(s.z), a3 = bf2f(s.w);
    int e = offs[node], end = offs[node + 1];
    for (; e + 4 <= end; e += 4) {
        int r0 = rclamp(rowidx[e], N),   r1 = rclamp(rowidx[e+1], N);
        int r2 = rclamp(rowidx[e+2], N), r3 = rclamp(rowidx[e+3], N);
        ushort4 u0 = *(const ushort4*)(Hn + (size_t)r0 * HID + c);
        ushort4 u1 = *(const ushort4*)(Hn + (size_t)r1 * HID + c);
        ushort4 u2 = *(const ushort4*)(Hn + (size_t)r2 * HID + c);
        ushort4 u3 = *(const ushort4*)(Hn + (size_t)r3 * HID + c);
        a0 += (bf2f(u0.x) + bf2f(u1.x)) + (bf2f(u2.x) + bf2f(u3.x));
        a1 += (bf2f(u0.y) + bf2f(u1.y)) + (bf2f(u2.y) + bf2f(u3.y));
        a2 += (bf2f(u0.z) + bf2f(u1.z)) + (bf2f(u2.z) + bf2f(u3.z));
        a3 += (bf2f(u0.w) + bf2f(u1.w)) + (bf2f(u2.w) + bf2f(u3.w));
    }
    for (; e < end; e++) {
        ushort4 u = *(const ushort4*)(Hn + (size_t)rclamp(rowidx[e], N) * HID + c);
        a0 += bf2f(u.x); a1 += bf2f(u.y); a2 += bf2f(u.z); a3 += bf2f(u.w);
    }
    float dv = dinv[node];
    ushort4 o = make_ushort4(f2bf(a0*dv), f2bf(a1*dv), f2bf(a2*dv), f2bf(a3*dv));
    *(ushort4*)(Y + (size_t)node * HID + c) = o;
}

__global__ void k_aggout(const unsigned short* __restrict__ G,
                         const int* __restrict__ offs, const int* __restrict__ rowidx,
                         const float* __restrict__ dinv, const float* __restrict__ bias,
                         float* __restrict__ out, int N) {
    int wid = threadIdx.x >> 6, lane = threadIdx.x & 63;
    int node = blockIdx.x * 4 + wid;
    if (node >= N) return;
    int c = lane * 2;
    ushort2 s = *(const ushort2*)(G + (size_t)node * NP3 + c);
    float a0 = bf2f(s.x), a1 = bf2f(s.y);
    int e = offs[node], end = offs[node + 1];
    for (; e + 4 <= end; e += 4) {
        int r0 = rclamp(rowidx[e], N),   r1 = rclamp(rowidx[e+1], N);
        int r2 = rclamp(rowidx[e+2], N), r3 = rclamp(rowidx[e+3], N);
        ushort2 u0 = *(const ushort2*)(G + (size_t)r0 * NP3 + c);
        ushort2 u1 = *(const ushort2*)(G + (size_t)r1 * NP3 + c);
        ushort2 u2 = *(const ushort2*)(G + (size_t)r2 * NP3 + c);
        ushort2 u3 = *(const ushort2*)(G + (size_t)r3 * NP3 + c);
        a0 += (bf2f(u0.x) + bf2f(u1.x)) + (bf2f(u2.x) + bf2f(u3.x));
        a1 += (bf2f(u0.y) + bf2f(u1.y)) + (bf2f(u2.y) + bf2f(u3.y));
    }
    for (; e < end; e++) {
        ushort2 u = *(const ushort2*)(G + (size_t)rclamp(rowidx[e], N) * NP3 + c);
        a0 += bf2f(u.x); a1 += bf2f(u.y);
    }
    float dv = dinv[node];
    if (c < OUT_F)     out[(size_t)node * OUT_F + c]     = fmaf(a0, dv, bias[c]);
    if (c + 1 < OUT_F) out[(size_t)node * OUT_F + c + 1] = fmaf(a1, dv, bias[c + 1]);
}

// ---- launch -----------------------------------------------------------------

extern "C" void kernel_launch(void* const* d_in, const int* in_sizes, int n_in,
                              void* d_out, int out_size, void* d_ws, size_t ws_size,
                              hipStream_t stream) {
    const float* x  = (const float*)d_in[0];
    const int*   ei = (const int*)d_in[1];
    const float* W1 = (const float*)d_in[2];
    const float* b1 = (const float*)d_in[3];
    const float* W2 = (const float*)d_in[4];
    const float* b2 = (const float*)d_in[5];
    const float* W3 = (const float*)d_in[6];
    const float* b3 = (const float*)d_in[7];
    float* out = (float*)d_out;

    const int N = in_sizes[0] / IN_F;     // 100000
    const int E = in_sizes[1] / 2;        // 1600000

    char* w = (char*)d_ws;
    size_t off = 0;
    auto alloc = [&](size_t bytes) -> char* {
        char* p = w + off;
        off += (bytes + 255) & ~(size_t)255;
        return p;
    };
    int*   cnt    = (int*)  alloc((size_t)N * 4);
    int*   offs   = (int*)  alloc((size_t)(N + 1) * 4);
    int*   fillc  = (int*)  alloc((size_t)N * 4);
    float* dinv   = (float*)alloc((size_t)N * 4);
    int*   flag   = (int*)  alloc(256);
    int*   rowidx = (int*)  alloc((size_t)E * 4);
    unsigned short* Bt1 = (unsigned short*)alloc((size_t)HID * KP1 * 2);
    unsigned short* Bt2 = (unsigned short*)alloc((size_t)HID * HID * 2);
    unsigned short* Bt3 = (unsigned short*)alloc((size_t)NP3 * HID * 2);
    unsigned short* bufA = (unsigned short*)alloc((size_t)N * HID * 2);  // Xs -> H1s -> H2
    unsigned short* bufB = (unsigned short*)alloc((size_t)N * HID * 2);  // Y1 -> Y2 -> G3
    unsigned short* Xs  = bufA;
    unsigned short* Y1  = bufB;
    unsigned short* H1s = bufA;
    unsigned short* Y2  = bufB;
    unsigned short* H2  = bufA;
    unsigned short* G3  = bufB;

    hipMemsetAsync(cnt, 0, (size_t)N * 4, stream);
    hipMemsetAsync(fillc, 0, (size_t)N * 4, stream);
    hipMemsetAsync(rowidx, 0, (size_t)E * 4, stream);

    k_detect<<<1, 64, 0, stream>>>(ei, flag, N);
    k_count<<<(E + 255) / 256, 256, 0, stream>>>(ei, flag, cnt, E, N);
    k_scan<<<1, 1024, 0, stream>>>(cnt, offs, dinv, N);
    k_fill<<<(E + 255) / 256, 256, 0, stream>>>(ei, flag, offs, fillc, rowidx, E, N);

    k_padx<<<(N * KP1 + 255) / 256, 256, 0, stream>>>(x, dinv, Xs, N);
    k_tr<<<(HID * KP1 + 255) / 256, 256, 0, stream>>>(W1, Bt1, IN_F, HID, KP1, HID);
    k_tr<<<(HID * HID + 255) / 256, 256, 0, stream>>>(W2, Bt2, HID, HID, HID, HID);
    k_tr<<<(NP3 * HID + 255) / 256, 256, 0, stream>>>(W3, Bt3, HID, OUT_F, HID, NP3);

    int gblocks = ((N + 15) / 16 + 3) / 4;   // 1563
    int aggg = (N + 3) / 4;                  // 25000

    // layer 1: aggregate-first, then GEMM (+b1, relu, *dinv)
    k_aggx<<<aggg, 256, 0, stream>>>(Xs, offs, rowidx, dinv, Y1, N);
    k_gemm1<<<gblocks, 256, 0, stream>>>(Y1, Bt1, dinv, b1, H1s, N, KP1);
    // layer 2: aggregate H1s, then GEMM (+b2, relu)
    k_agg256<<<aggg, 256, 0, stream>>>(H1s, offs, rowidx, dinv, Y2, N);
    k_gemm2<<<gblocks, 256, 0, stream>>>(Y2, Bt2, dinv, b2, H2, N, HID);
    // layer 3: GEMM (*dinv), then aggregate (+b3), f32 out
    k_gemm3<<<gblocks, 256, 0, stream>>>(H2, Bt3, dinv, b3, G3, N, HID);
    k_aggout<<<aggg, 256, 0, stream>>>(G3, offs, rowidx, dinv, b3, out, N);

    (void)n_in; (void)out_size; (void)ws_size;
}

// Round 8
// 710.427 us; speedup vs baseline: 1.2833x; 1.1515x over previous
//
#include <hip/hip_runtime.h>

// GCN 3-layer forward on MI355X.
// Pipeline (A_hat (X W) = (A_hat X) W):
//   aggx:  Y1 = A_hat X         GEMM1: H1s = dinv*relu(Y1 W1 + b1)
//   agg256: Y2 = A_hat H1       GEMM2: H2 = relu(Y2 W2 + b2)
//   GEMM3: G3 = dinv*(H2 W3)    aggout: out = dinv[c]*(sum G3[r]+G3[c]) + b3 (f32)
// GEMM: m97-style LDS-tiled MFMA (128x128 tile, BK=32, global_load_lds w=16,
// ds_read_b128 frags, 4 waves x 64x64). M padded to 100096; padded rows read
// 0xAA poison (finite bf16/f32), outputs never consumed.
// CSR build: round-3-proven (atomics only on memset-initialized arrays),
// rowidx clamped at read time.

#define IN_F 50
#define HID  256
#define OUT_F 121
#define KP1  64      // layer-1 width padded 50->64
#define NP3  128     // layer-3 N padded 121->128
#define MPAD 100096  // 782 * 128

typedef __attribute__((ext_vector_type(8))) short bf16x8;
typedef __attribute__((ext_vector_type(4))) float f32x4;

__device__ __forceinline__ float bf2f(unsigned short u) {
    union { unsigned int i; float f; } x; x.i = ((unsigned int)u) << 16; return x.f;
}
__device__ __forceinline__ unsigned short f2bf(float f) {
    union { float f; unsigned int i; } x; x.f = f;
    unsigned int r = x.i + 0x7FFFu + ((x.i >> 16) & 1u);  // RNE
    return (unsigned short)(r >> 16);
}

__device__ __forceinline__ void gl2lds16(const void* g, void* l) {
    __builtin_amdgcn_global_load_lds(
        (const __attribute__((address_space(1))) void*)g,
        (__attribute__((address_space(3))) void*)l, 16, 0, 0);
}

// ---- edge dtype detection (int64 vs int32), 64-lane parallel ----------------
__global__ void k_detect(const int* __restrict__ ei, int* __restrict__ flag, int N) {
    int i = threadIdx.x;
    int lo = ei[2 * i], hi = ei[2 * i + 1];
    int bad = (hi != 0) || ((unsigned)lo >= (unsigned)N);
    unsigned long long m = __ballot(bad);
    if (threadIdx.x == 0) *flag = (m == 0ULL) ? 1 : 0;
}

// ---- CSR build --------------------------------------------------------------

__global__ void k_count(const int* __restrict__ ei, const int* __restrict__ flag,
                        int* __restrict__ cnt, int E, int N) {
    int t = blockIdx.x * blockDim.x + threadIdx.x;
    if (t >= E) return;
    int f = *flag;
    int c = f ? ei[2 * (E + t)] : ei[E + t];
    c = min(max(c, 0), N - 1);
    atomicAdd(&cnt[c], 1);
}

__global__ __launch_bounds__(1024) void k_scan(const int* __restrict__ cnt,
                                               int* __restrict__ offs,
                                               float* __restrict__ dinv, int n) {
    __shared__ int wsum[16];
    __shared__ int s_carry;
    int lane = threadIdx.x & 63, wid = threadIdx.x >> 6;
    if (threadIdx.x == 0) s_carry = 0;
    __syncthreads();
    for (int base = 0; base < n; base += 4096) {
        int i0 = base + (int)threadIdx.x * 4;
        int v0 = (i0 + 0 < n) ? cnt[i0 + 0] : 0;
        int v1 = (i0 + 1 < n) ? cnt[i0 + 1] : 0;
        int v2 = (i0 + 2 < n) ? cnt[i0 + 2] : 0;
        int v3 = (i0 + 3 < n) ? cnt[i0 + 3] : 0;
        int s1 = v0 + v1, s2 = s1 + v2, tsum = s2 + v3;
        int x = tsum;
        #pragma unroll
        for (int d = 1; d < 64; d <<= 1) {
            int y = __shfl_up(x, d, 64);
            if (lane >= d) x += y;
        }
        if (lane == 63) wsum[wid] = x;
        __syncthreads();
        int wpre = 0;
        #pragma unroll
        for (int j = 0; j < 16; j++) wpre += (j < wid) ? wsum[j] : 0;
        int carry = s_carry;
        int e0 = carry + wpre + x - tsum;
        if (i0 + 0 < n) { offs[i0+0]=e0;    dinv[i0+0]=rsqrtf((float)(v0+1)); }
        if (i0 + 1 < n) { offs[i0+1]=e0+v0; dinv[i0+1]=rsqrtf((float)(v1+1)); }
        if (i0 + 2 < n) { offs[i0+2]=e0+s1; dinv[i0+2]=rsqrtf((float)(v2+1)); }
        if (i0 + 3 < n) { offs[i0+3]=e0+s2; dinv[i0+3]=rsqrtf((float)(v3+1)); }
        __syncthreads();
        if (threadIdx.x == 1023) s_carry = carry + wpre + x;
        __syncthreads();
    }
    if (threadIdx.x == 0) offs[n] = s_carry;
}

__global__ void k_fill(const int* __restrict__ ei, const int* __restrict__ flag,
                       const int* __restrict__ offs,
                       int* __restrict__ fillc, int* __restrict__ rowidx, int E, int N) {
    int t = blockIdx.x * blockDim.x + threadIdx.x;
    if (t >= E) return;
    int f = *flag;
    int c = f ? ei[2 * (E + t)] : ei[E + t];
    int r = f ? ei[2 * t] : ei[t];
    c = min(max(c, 0), N - 1);
    r = min(max(r, 0), N - 1);
    int pos = offs[c] + atomicAdd(&fillc[c], 1);
    if ((unsigned)pos < (unsigned)E) rowidx[pos] = r;
}

// ---- input prep -------------------------------------------------------------

__global__ void k_padx(const float* __restrict__ x, const float* __restrict__ dinv,
                       unsigned short* __restrict__ Xs, int N) {
    int idx = blockIdx.x * blockDim.x + threadIdx.x;
    if (idx >= N * KP1) return;
    int node = idx >> 6, k = idx & 63;
    Xs[idx] = (k < IN_F) ? f2bf(dinv[node] * x[node * IN_F + k]) : (unsigned short)0;
}

__global__ void k_tr(const float* __restrict__ W, unsigned short* __restrict__ Bt,
                     int K, int Nw, int Kp, int Np) {
    int idx = blockIdx.x * blockDim.x + threadIdx.x;
    if (idx >= Np * Kp) return;
    int nn = idx / Kp, k = idx - nn * Kp;
    Bt[idx] = (k < K && nn < Nw) ? f2bf(W[k * Nw + nn]) : (unsigned short)0;
}

// ---- LDS-tiled GEMM (m97 structure) -----------------------------------------
// C[m][n] = post(sum_k A[m][k]*Bt[n][k]); A [MPAD x K], Bt [Nout x K], C [MPAD x Nout].
// Block: 256 thr = 4 waves (2x2), tile 128(M) x 128(N), BK=32. grid = (MPAD/128, Nout/128).
__global__ __launch_bounds__(256) void k_gemm_lds(const unsigned short* __restrict__ A,
                                                  const unsigned short* __restrict__ Bt,
                                                  const float* __restrict__ dinv,
                                                  const float* __restrict__ bias,
                                                  unsigned short* __restrict__ C,
                                                  int K, int Nout,
                                                  int BIAS, int RELU, int SCALE) {
    __shared__ char lds[16384];   // A tile [128][32] bf16 @0, B tile @8192
    const int tid = threadIdx.x;
    const int wid = tid >> 6, lane = tid & 63;
    const int wm = wid & 1, wn = wid >> 1;
    const int quad = lane >> 4, ml = lane & 15;
    const int m0 = blockIdx.x * 128;
    const int n0g = blockIdx.y * 128;

    f32x4 acc[4][4];
    #pragma unroll
    for (int a = 0; a < 4; a++)
        #pragma unroll
        for (int b = 0; b < 4; b++) acc[a][b] = (f32x4){0.f, 0.f, 0.f, 0.f};

    for (int kk = 0; kk < K; kk += 32) {
        #pragma unroll
        for (int r = 0; r < 2; r++) {
            int c = r * 256 + tid;            // chunk 0..511; row=c>>2, quarter=c&3
            int row = c >> 2, q = c & 3;
            gl2lds16(A  + (size_t)(m0  + row) * K + kk + q * 8, lds + c * 16);
            gl2lds16(Bt + (size_t)(n0g + row) * K + kk + q * 8, lds + 8192 + c * 16);
        }
        __syncthreads();   // drains vmcnt: LDS writes visible
        bf16x8 af[4], bfv[4];
        #pragma unroll
        for (int mf = 0; mf < 4; mf++)
            af[mf] = *(const bf16x8*)(lds + ((wm * 64 + mf * 16 + ml) * 64 + quad * 16));
        #pragma unroll
        for (int nf = 0; nf < 4; nf++)
            bfv[nf] = *(const bf16x8*)(lds + 8192 + ((wn * 64 + nf * 16 + ml) * 64 + quad * 16));
        #pragma unroll
        for (int mf = 0; mf < 4; mf++)
            #pragma unroll
            for (int nf = 0; nf < 4; nf++)
                acc[mf][nf] = __builtin_amdgcn_mfma_f32_16x16x32_bf16(af[mf], bfv[nf], acc[mf][nf], 0, 0, 0);
        __syncthreads();   // protect LDS before next stage
    }

    #pragma unroll
    for (int mf = 0; mf < 4; mf++) {
        int r0 = m0 + wm * 64 + mf * 16 + quad * 4;
        float dd[4] = {1.f, 1.f, 1.f, 1.f};
        if (SCALE) { dd[0]=dinv[r0]; dd[1]=dinv[r0+1]; dd[2]=dinv[r0+2]; dd[3]=dinv[r0+3]; }
        #pragma unroll
        for (int nf = 0; nf < 4; nf++) {
            int col = n0g + wn * 64 + nf * 16 + ml;
            float bb = BIAS ? bias[col] : 0.f;
            #pragma unroll
            for (int i = 0; i < 4; i++) {
                float v = acc[mf][nf][i] + bb;
                if (RELU) v = fmaxf(v, 0.f);
                v *= dd[i];
                C[(size_t)(r0 + i) * Nout + col] = f2bf(v);
            }
        }
    }
}

// ---- aggregation kernels (gather, unroll-4, read-side index clamp) ----------

__device__ __forceinline__ int rclamp(int r, int N) { return min(max(r, 0), N - 1); }

__global__ void k_aggx(const unsigned short* __restrict__ Xs,
                       const int* __restrict__ offs, const int* __restrict__ rowidx,
                       const float* __restrict__ dinv, unsigned short* __restrict__ Y, int N) {
    int wid = threadIdx.x >> 6, lane = threadIdx.x & 63;
    int node = blockIdx.x * 4 + wid;
    if (node >= N) return;
    float a = bf2f(Xs[(size_t)node * KP1 + lane]);
    int e = offs[node], end = offs[node + 1];
    for (; e + 4 <= end; e += 4) {
        int r0 = rclamp(rowidx[e], N),   r1 = rclamp(rowidx[e+1], N);
        int r2 = rclamp(rowidx[e+2], N), r3 = rclamp(rowidx[e+3], N);
        float g0 = bf2f(Xs[(size_t)r0 * KP1 + lane]);
        float g1 = bf2f(Xs[(size_t)r1 * KP1 + lane]);
        float g2 = bf2f(Xs[(size_t)r2 * KP1 + lane]);
        float g3 = bf2f(Xs[(size_t)r3 * KP1 + lane]);
        a += (g0 + g1) + (g2 + g3);
    }
    for (; e < end; e++) a += bf2f(Xs[(size_t)rclamp(rowidx[e], N) * KP1 + lane]);
    Y[(size_t)node * KP1 + lane] = f2bf(a * dinv[node]);
}

__global__ void k_agg256(const unsigned short* __restrict__ Hn,
                         const int* __restrict__ offs, const int* __restrict__ rowidx,
                         const float* __restrict__ dinv, unsigned short* __restrict__ Y, int N) {
    int wid = threadIdx.x >> 6, lane = threadIdx.x & 63;
    int node = blockIdx.x * 4 + wid;
    if (node >= N) return;
    int c = lane * 4;
    ushort4 s = *(const ushort4*)(Hn + (size_t)node * HID + c);
    float a0 = bf2f(s.x), a1 = bf2f(s.y), a2 = bf2f(s.z), a3 = bf2f(s.w);
    int e = offs[node], end = offs[node + 1];
    for (; e + 4 <= end; e += 4) {
        int r0 = rclamp(rowidx[e], N),   r1 = rclamp(rowidx[e+1], N);
        int r2 = rclamp(rowidx[e+2], N), r3 = rclamp(rowidx[e+3], N);
        ushort4 u0 = *(const ushort4*)(Hn + (size_t)r0 * HID + c);
        ushort4 u1 = *(const ushort4*)(Hn + (size_t)r1 * HID + c);
        ushort4 u2 = *(const ushort4*)(Hn + (size_t)r2 * HID + c);
        ushort4 u3 = *(const ushort4*)(Hn + (size_t)r3 * HID + c);
        a0 += (bf2f(u0.x) + bf2f(u1.x)) + (bf2f(u2.x) + bf2f(u3.x));
        a1 += (bf2f(u0.y) + bf2f(u1.y)) + (bf2f(u2.y) + bf2f(u3.y));
        a2 += (bf2f(u0.z) + bf2f(u1.z)) + (bf2f(u2.z) + bf2f(u3.z));
        a3 += (bf2f(u0.w) + bf2f(u1.w)) + (bf2f(u2.w) + bf2f(u3.w));
    }
    for (; e < end; e++) {
        ushort4 u = *(const ushort4*)(Hn + (size_t)rclamp(rowidx[e], N) * HID + c);
        a0 += bf2f(u.x); a1 += bf2f(u.y); a2 += bf2f(u.z); a3 += bf2f(u.w);
    }
    float dv = dinv[node];
    ushort4 o = make_ushort4(f2bf(a0*dv), f2bf(a1*dv), f2bf(a2*dv), f2bf(a3*dv));
    *(ushort4*)(Y + (size_t)node * HID + c) = o;
}

__global__ void k_aggout(const unsigned short* __restrict__ G,
                         const int* __restrict__ offs, const int* __restrict__ rowidx,
                         const float* __restrict__ dinv, const float* __restrict__ bias,
                         float* __restrict__ out, int N) {
    int wid = threadIdx.x >> 6, lane = threadIdx.x & 63;
    int node = blockIdx.x * 4 + wid;
    if (node >= N) return;
    int c = lane * 2;
    ushort2 s = *(const ushort2*)(G + (size_t)node * NP3 + c);
    float a0 = bf2f(s.x), a1 = bf2f(s.y);
    int e = offs[node], end = offs[node + 1];
    for (; e + 4 <= end; e += 4) {
        int r0 = rclamp(rowidx[e], N),   r1 = rclamp(rowidx[e+1], N);
        int r2 = rclamp(rowidx[e+2], N), r3 = rclamp(rowidx[e+3], N);
        ushort2 u0 = *(const ushort2*)(G + (size_t)r0 * NP3 + c);
        ushort2 u1 = *(const ushort2*)(G + (size_t)r1 * NP3 + c);
        ushort2 u2 = *(const ushort2*)(G + (size_t)r2 * NP3 + c);
        ushort2 u3 = *(const ushort2*)(G + (size_t)r3 * NP3 + c);
        a0 += (bf2f(u0.x) + bf2f(u1.x)) + (bf2f(u2.x) + bf2f(u3.x));
        a1 += (bf2f(u0.y) + bf2f(u1.y)) + (bf2f(u2.y) + bf2f(u3.y));
    }
    for (; e < end; e++) {
        ushort2 u = *(const ushort2*)(G + (size_t)rclamp(rowidx[e], N) * NP3 + c);
        a0 += bf2f(u.x); a1 += bf2f(u.y);
    }
    float dv = dinv[node];
    if (c < OUT_F)     out[(size_t)node * OUT_F + c]     = fmaf(a0, dv, bias[c]);
    if (c + 1 < OUT_F) out[(size_t)node * OUT_F + c + 1] = fmaf(a1, dv, bias[c + 1]);
}

// ---- launch -----------------------------------------------------------------

extern "C" void kernel_launch(void* const* d_in, const int* in_sizes, int n_in,
                              void* d_out, int out_size, void* d_ws, size_t ws_size,
                              hipStream_t stream) {
    const float* x  = (const float*)d_in[0];
    const int*   ei = (const int*)d_in[1];
    const float* W1 = (const float*)d_in[2];
    const float* b1 = (const float*)d_in[3];
    const float* W2 = (const float*)d_in[4];
    const float* b2 = (const float*)d_in[5];
    const float* W3 = (const float*)d_in[6];
    const float* b3 = (const float*)d_in[7];
    float* out = (float*)d_out;

    const int N = in_sizes[0] / IN_F;     // 100000
    const int E = in_sizes[1] / 2;        // 1600000

    char* w = (char*)d_ws;
    size_t off = 0;
    auto alloc = [&](size_t bytes) -> char* {
        char* p = w + off;
        off += (bytes + 255) & ~(size_t)255;
        return p;
    };
    int*   cnt    = (int*)  alloc((size_t)N * 4);
    int*   offs   = (int*)  alloc((size_t)(N + 1) * 4);
    int*   fillc  = (int*)  alloc((size_t)N * 4);
    float* dinv   = (float*)alloc((size_t)MPAD * 4);   // padded: GEMM epilogue reads r<MPAD
    int*   flag   = (int*)  alloc(256);
    int*   rowidx = (int*)  alloc((size_t)E * 4);
    unsigned short* Bt1 = (unsigned short*)alloc((size_t)HID * KP1 * 2);
    unsigned short* Bt2 = (unsigned short*)alloc((size_t)HID * HID * 2);
    unsigned short* Bt3 = (unsigned short*)alloc((size_t)NP3 * HID * 2);
    unsigned short* bufA = (unsigned short*)alloc((size_t)MPAD * HID * 2);  // Xs -> H1s -> H2
    unsigned short* bufB = (unsigned short*)alloc((size_t)MPAD * HID * 2);  // Y1 -> Y2 -> G3
    unsigned short* Xs  = bufA;
    unsigned short* Y1  = bufB;
    unsigned short* H1s = bufA;
    unsigned short* Y2  = bufB;
    unsigned short* H2  = bufA;
    unsigned short* G3  = bufB;

    hipMemsetAsync(cnt, 0, (size_t)N * 4, stream);
    hipMemsetAsync(fillc, 0, (size_t)N * 4, stream);
    hipMemsetAsync(rowidx, 0, (size_t)E * 4, stream);

    k_detect<<<1, 64, 0, stream>>>(ei, flag, N);
    k_count<<<(E + 255) / 256, 256, 0, stream>>>(ei, flag, cnt, E, N);
    k_scan<<<1, 1024, 0, stream>>>(cnt, offs, dinv, N);
    k_fill<<<(E + 255) / 256, 256, 0, stream>>>(ei, flag, offs, fillc, rowidx, E, N);

    k_padx<<<(N * KP1 + 255) / 256, 256, 0, stream>>>(x, dinv, Xs, N);
    k_tr<<<(HID * KP1 + 255) / 256, 256, 0, stream>>>(W1, Bt1, IN_F, HID, KP1, HID);
    k_tr<<<(HID * HID + 255) / 256, 256, 0, stream>>>(W2, Bt2, HID, HID, HID, HID);
    k_tr<<<(NP3 * HID + 255) / 256, 256, 0, stream>>>(W3, Bt3, HID, OUT_F, HID, NP3);

    dim3 g12(MPAD / 128, HID / 128);   // (782, 2)
    dim3 g3(MPAD / 128, NP3 / 128);    // (782, 1)
    int aggg = (N + 3) / 4;            // 25000

    // layer 1: aggregate-first, then GEMM (+b1, relu, *dinv)
    k_aggx<<<aggg, 256, 0, stream>>>(Xs, offs, rowidx, dinv, Y1, N);
    k_gemm_lds<<<g12, 256, 0, stream>>>(Y1, Bt1, dinv, b1, H1s, KP1, HID, 1, 1, 1);
    // layer 2: aggregate H1s, then GEMM (+b2, relu)
    k_agg256<<<aggg, 256, 0, stream>>>(H1s, offs, rowidx, dinv, Y2, N);
    k_gemm_lds<<<g12, 256, 0, stream>>>(Y2, Bt2, dinv, b2, H2, HID, HID, 1, 1, 0);
    // layer 3: GEMM (*dinv), then aggregate (+b3), f32 out
    k_gemm_lds<<<g3, 256, 0, stream>>>(H2, Bt3, dinv, b3, G3, HID, NP3, 0, 0, 1);
    k_aggout<<<aggg, 256, 0, stream>>>(G3, offs, rowidx, dinv, b3, out, N);

    (void)n_in; (void)out_size; (void)ws_size;
}